// Round 6
// baseline (442.166 us; speedup 1.0000x reference)
//
#include <hip/hip_runtime.h>

// out[b,c,p] = alpha[slot[b,p], c] * x[b,c,p] + beta[slot[b,p], c]
//   x: [B=32, C=2048, HW=1024] fp32, slot: [B, 1024] int32 in [0,256)
//   alpha/beta: [256, 2048] fp32
//
// Block = (image group of 8, channel group of 8). 256 threads, 1024 blocks
// (exactly 4 blocks/CU, whole grid co-resident, one staging phase total).
// R6: single change vs R5 (fa ~96.6 us, 92% of copy ceiling):
//  - REMOVE nontemporal hints on the x loads and out stores. The nt/sc
//    cache-bypass bits were protecting table L2 residency that no longer
//    matters (tables staged once per block since R2, 16 MB total), and
//    they are the one structural difference between our stream and the
//    6.29 TB/s copy / 6.5 TB/s fill patterns that set the ceiling.
//    A/B probe: improvement -> keep; neutral/regression -> nt innocent,
//    declare roofline (residual = mixed-stream ceiling + dispatch gaps).
//  - Everything else identical to R5: scalar lds[ch][slot] bank layout,
//    explicit 1-image ping-pong pipeline (loads of i+1 issued before
//    stores of i; consume waits at vmcnt(8), never a store drain),
//    prologue x-prefetch between table loads and ds_writes (barrier
//    waits at vmcnt(9)).

typedef float  f4 __attribute__((ext_vector_type(4)));
typedef int    i4 __attribute__((ext_vector_type(4)));

#define CH   2048
#define HW   1024
#define NS   256
#define CPB  8              // channels per block
#define NCG  (CH / CPB)     // 256 channel-group blocks
#define IPB  8              // images per block

__global__ __launch_bounds__(256, 4) void fa_kernel(
    const float* __restrict__ x,
    const int*   __restrict__ slot,
    const float* __restrict__ alpha,
    const float* __restrict__ beta,
    float*       __restrict__ out)
{
    __shared__ float lds_a[CPB][NS];   // 8 KB, gather bank = slot % 32
    __shared__ float lds_b[CPB][NS];   // 8 KB

    const int cg = blockIdx.x & (NCG - 1);
    const int bg = blockIdx.x >> 8;          // /NCG, in [0,4)
    const int b0 = bg * IPB;
    const int c0 = cg * CPB;
    const int t  = threadIdx.x;
    const int p  = t << 2;

    // ---- table staging loads first (L2 latency) ----
    const f4 ar0 = *(const f4*)(alpha + (size_t)t * CH + c0);
    const f4 ar1 = *(const f4*)(alpha + (size_t)t * CH + c0 + 4);
    const f4 br0 = *(const f4*)(beta  + (size_t)t * CH + c0);
    const f4 br1 = *(const f4*)(beta  + (size_t)t * CH + c0 + 4);

    // ---- prologue prefetch for image 0, issued BEFORE the ds_writes so
    // the pre-barrier waitcnt is vmcnt(9), not a full drain ----
    i4 s[2];
    f4 xv[2][CPB];
    s[0] = *(const i4*)(slot + (size_t)b0 * HW + p);
    const size_t base0 = ((size_t)b0 * CH + c0) * HW + p;
#pragma unroll
    for (int k = 0; k < CPB; ++k)
        xv[0][k] = *(const f4*)(x + base0 + (size_t)k * HW);

    // transpose table rows into per-channel scalar arrays (stride-1 writes)
#pragma unroll
    for (int k = 0; k < 4; ++k) {
        lds_a[k][t]     = ar0[k];
        lds_a[4 + k][t] = ar1[k];
        lds_b[k][t]     = br0[k];
        lds_b[4 + k][t] = br1[k];
    }

    __syncthreads();

    // ---- explicit software pipeline over IPB images ----
#pragma unroll
    for (int i = 0; i < IPB; ++i) {
        const int cur = i & 1;          // compile-time after full unroll
        const int nxt = cur ^ 1;

        // issue next image's loads FIRST (before this image's stores)
        if (i + 1 < IPB) {
            const int bn = b0 + i + 1;
            s[nxt] = *(const i4*)(slot + (size_t)bn * HW + p);
            const size_t basen = ((size_t)bn * CH + c0) * HW + p;
#pragma unroll
            for (int k = 0; k < CPB; ++k)
                xv[nxt][k] = *(const f4*)(x + basen + (size_t)k * HW);
        }

        const int    b    = b0 + i;
        const size_t base = ((size_t)b * CH + c0) * HW + p;
        const i4     sc   = s[cur];

#pragma unroll
        for (int k = 0; k < CPB; ++k) {
            const float a0 = lds_a[k][sc.x], a1 = lds_a[k][sc.y],
                        a2 = lds_a[k][sc.z], a3 = lds_a[k][sc.w];
            const float q0 = lds_b[k][sc.x], q1 = lds_b[k][sc.y],
                        q2 = lds_b[k][sc.z], q3 = lds_b[k][sc.w];
            f4 o;
            o[0] = a0 * xv[cur][k][0] + q0;
            o[1] = a1 * xv[cur][k][1] + q1;
            o[2] = a2 * xv[cur][k][2] + q2;
            o[3] = a3 * xv[cur][k][3] + q3;
            *(f4*)(out + base + (size_t)k * HW) = o;
        }
    }
}

extern "C" void kernel_launch(void* const* d_in, const int* in_sizes, int n_in,
                              void* d_out, int out_size, void* d_ws, size_t ws_size,
                              hipStream_t stream) {
    const float* x     = (const float*)d_in[0];
    const int*   slot  = (const int*)d_in[1];
    const float* alpha = (const float*)d_in[2];
    const float* beta  = (const float*)d_in[3];
    float*       out   = (float*)d_out;

    const int B = in_sizes[0] / (CH * HW);   // 32
    dim3 grid((B / IPB) * NCG);               // 1024 blocks
    dim3 block(256);
    fa_kernel<<<grid, block, 0, stream>>>(x, slot, alpha, beta, out);
}